// Round 10
// baseline (1165.138 us; speedup 1.0000x reference)
//
#include <hip/hip_runtime.h>
#include <hip/hip_bf16.h>

typedef unsigned short u16;
typedef unsigned int u32;

typedef __bf16 bf16x8 __attribute__((ext_vector_type(8)));
typedef float f32x4 __attribute__((ext_vector_type(4)));

__device__ __forceinline__ float b2f_lo(u32 u) { return __uint_as_float(u << 16); }
__device__ __forceinline__ float b2f_hi(u32 u) { return __uint_as_float(u & 0xffff0000u); }
__device__ __forceinline__ u16 f2b(float f) {
    u32 u = __float_as_uint(f);
    u32 r = u + 0x7fffu + ((u >> 16) & 1u);   // round-to-nearest-even
    return (u16)(r >> 16);
}

// ---------------- small utility kernels ----------------

__global__ void softmax_small(const float* __restrict__ att, float* __restrict__ mask, int K) {
    if (threadIdx.x == 0) {
        float m = -3.4e38f;
        for (int i = 0; i < K; ++i) m = fmaxf(m, att[i]);
        float s = 0.f;
        for (int i = 0; i < K; ++i) { float e = __expf(att[i] - m); mask[i] = e; s += e; }
        for (int i = 0; i < K; ++i) mask[i] /= s;
    }
}

__global__ void pack_bf16(const float* __restrict__ src, u16* __restrict__ dst, long n) {
    long g = (long)blockIdx.x * 256 + threadIdx.x;   // one float4 per thread
    if (g * 4 >= n) return;
    float4 v = reinterpret_cast<const float4*>(src)[g];
    ushort4 o;
    o.x = f2b(v.x); o.y = f2b(v.y); o.z = f2b(v.z); o.w = f2b(v.w);
    reinterpret_cast<ushort4*>(dst)[g] = o;
}

// transpose-pack all six 256x256 f32 weights -> bf16 [6][256][256] (row = out col)
__global__ void pack_wt_all(const float* __restrict__ W_mlp, const float* __restrict__ We1,
                            const float* __restrict__ We2, const float* __restrict__ Wh,
                            u16* __restrict__ wt) {
    int idx = blockIdx.x * 256 + threadIdx.x;   // < 65536
    int y = blockIdx.y;
    const float* W = (y == 0) ? W_mlp : (y == 1) ? We1 : (y == 2) ? We2
                                      : (Wh + (size_t)(y - 3) * 65536);
    int n = idx >> 8, k = idx & 255;
    wt[(size_t)y * 65536 + idx] = f2b(W[k * 256 + n]);
}

// pack Wc [NB*256][O] -> per-branch transposed bf16 [NB][48][256], zero-padded cols
__global__ void pack_wct(const float* __restrict__ Wc, u16* __restrict__ Wct, int O, int NB) {
    int idx = blockIdx.x * 256 + threadIdx.x;
    if (idx >= NB * 48 * 256) return;
    int b = idx / (48 * 256);
    int r = idx - b * 48 * 256;
    int n = r >> 8, k = r & 255;
    float v = (n < O) ? Wc[((size_t)(b * 256 + k)) * O + n] : 0.f;
    Wct[idx] = f2b(v);
}

// ---------------- bucket-local CSR build (no global random atomics) ----------------
#define BSHIFT 8
#define BMAX 256          // N <= 65536 -> at most 256 buckets
#define BCAP 12288        // fixed bucket capacity; mean E/B ~8163
#define BINCHUNK 8192

// phase 1: LDS histogram -> one reservation atomic per bucket -> LDS bucket-sort
// of the chunk's edges -> bucket-run writes with CONSECUTIVE lanes.
__global__ __launch_bounds__(256) void bin_edges(
    const int* __restrict__ ei, const int* __restrict__ nei, int E, int B,
    int* __restrict__ bcnt, u32* __restrict__ binned) {
    int set = blockIdx.y;
    const int* src = (set == 0) ? ei : (nei + (size_t)(set - 1) * 2 * E);
    const int* dst = src + E;
    __shared__ u32 ebuf[BINCHUNK];
    __shared__ int hist[BMAX], resv[BMAX], lbase[BMAX], lcur[BMAX], s[BMAX];
    int t = threadIdx.x;
    hist[t] = 0; lcur[t] = 0;
    __syncthreads();
    int base = blockIdx.x * BINCHUNK;
    int lim = min(base + BINCHUNK, E);
    for (int i = base + t; i < lim; i += 256)
        atomicAdd(&hist[dst[i] >> BSHIFT], 1);
    __syncthreads();
    int h = hist[t];
    if (h > 0) resv[t] = atomicAdd(&bcnt[set * BMAX + t], h);
    s[t] = h;
    __syncthreads();
    for (int off = 1; off < 256; off <<= 1) {
        int x = s[t];
        int add = (t >= off) ? s[t - off] : 0;
        __syncthreads();
        s[t] = x + add;
        __syncthreads();
    }
    lbase[t] = s[t] - h;
    __syncthreads();
    for (int i = base + t; i < lim; i += 256) {
        int d = dst[i];
        int b = d >> BSHIFT;
        int p = atomicAdd(&lcur[b], 1);
        ebuf[lbase[b] + p] = (u32)src[i] | ((u32)d << 16);
    }
    __syncthreads();
    int cnt = lim - base;
    for (int i = t; i < cnt; i += 256) {
        u32 pk = ebuf[i];
        int b = (int)(pk >> (16 + BSHIFT));
        int gpos = resv[b] + (i - lbase[b]);
        if (gpos < BCAP)
            binned[((size_t)set * BMAX + b) * BCAP + gpos] = pk;
    }
}

// phase 2: exclusive scan of bucket totals -> bucket bases; rp[N] = E
__global__ void bscan(const int* __restrict__ bcnt, int* __restrict__ bbase,
                      int* __restrict__ rp, int N, int E, int B) {
    int set = blockIdx.x, t = threadIdx.x;
    int v = (t < B) ? bcnt[set * BMAX + t] : 0;
    __shared__ int s[256];
    s[t] = v; __syncthreads();
    for (int off = 1; off < 256; off <<= 1) {
        int x = s[t];
        int add = (t >= off) ? s[t - off] : 0;
        __syncthreads();
        s[t] = x + add;
        __syncthreads();
    }
    bbase[set * BMAX + t] = s[t] - v;
    if (t == 0) rp[(size_t)set * (N + 1) + N] = E;
}

// phase 3: one block per (set,bucket). LDS degree histogram -> dinv + rp,
// then scatter u16 colAll with LDS cursors into the bucket's contiguous span.
__global__ __launch_bounds__(256) void bucket_build(
    const u32* __restrict__ binned, const int* __restrict__ bcnt,
    const int* __restrict__ bbase, int* __restrict__ rp, float* __restrict__ dinv,
    u16* __restrict__ colAll, int E, int N) {
    int set = blockIdx.y;
    int b = blockIdx.x;
    int t = threadIdx.x;
    int nb = bcnt[set * BMAX + b];
    int base = bbase[set * BMAX + b];
    const u32* bin = binned + ((size_t)set * BMAX + b) * BCAP;
    __shared__ int s[256], lcur[256];
    s[t] = 0; lcur[t] = 0;
    __syncthreads();
    for (int i = t; i < nb; i += 256)
        atomicAdd(&s[(bin[i] >> 16) & 255], 1);
    __syncthreads();
    int deg = s[t];
    __syncthreads();
    for (int off = 1; off < 256; off <<= 1) {
        int x = s[t];
        int add = (t >= off) ? s[t - off] : 0;
        __syncthreads();
        s[t] = x + add;
        __syncthreads();
    }
    int ex = s[t] - deg;
    __syncthreads();
    s[t] = ex;
    int node = (b << BSHIFT) + t;
    if (node < N) {
        rp[(size_t)set * (N + 1) + node] = base + ex;
        dinv[(size_t)set * N + node] = rsqrtf((float)(deg + 1));
    }
    __syncthreads();
    for (int i = t; i < nb; i += 256) {
        u32 pk = bin[i];
        int dl = (int)((pk >> 16) & 255);
        int pos = base + s[dl] + atomicAdd(&lcur[dl], 1);
        colAll[(size_t)set * E + pos] = (u16)(pk & 0xffffu);
    }
}

// ---------------- main GEMM: [M,256] x [256,256] (Bt transposed) ----------------
// Output is ALWAYS chunk-major [8][M][32] bf16.
// IN_CM: 0 = A row-major [M][256], 1 = A chunk-major [8][M][32]
// MODE 0: relu(acc + bias[col]) * mask[maskIdx]   (mlp)
// MODE 1: acc * dinv[row]                          (pre-aggregation scale)
#define SA 72   // LDS row stride in bf16 elems (64 + 8 pad)

template <int IN_CM, int MODE>
__global__ __launch_bounds__(256) void gemm_k256(
    const u16* __restrict__ A, const u16* __restrict__ Bt, u16* __restrict__ out,
    const float* __restrict__ bias, const float* __restrict__ dinv,
    const float* __restrict__ maskp, int maskIdx, int M) {
    __shared__ alignas(16) u16 lsA[128 * SA];
    __shared__ alignas(16) u16 lsB[128 * SA];
    const int tid = threadIdx.x;
    const int rowBase = blockIdx.x * 128;
    const int colBase = blockIdx.y * 128;
    const int w = tid >> 6, l = tid & 63;
    const int wm = w >> 1, wn = w & 1;
    const int lrow = l & 15, lkg = l >> 4;
    f32x4 acc[4][4] = {};

    for (int kt = 0; kt < 4; ++kt) {
        const int k0 = kt * 64;
#pragma unroll
        for (int q = 0; q < 4; ++q) {                 // 1024 16B granules per tile
            int g = q * 256 + tid;
            int m = g >> 3, gq = g & 7;               // 8 granules (64 bf16) per row
            int grow = rowBase + m;
            int k = k0 + gq * 8;
            uint4 v = make_uint4(0, 0, 0, 0);
            if (grow < M) {
                const u16* ap = IN_CM
                    ? (A + ((size_t)(k >> 5) * M + grow) * 32 + (k & 31))
                    : (A + (size_t)grow * 256 + k);
                v = *reinterpret_cast<const uint4*>(ap);
            }
            *reinterpret_cast<uint4*>(&lsA[m * SA + gq * 8]) = v;
            uint4 vb = *reinterpret_cast<const uint4*>(Bt + (size_t)(colBase + m) * 256 + k);
            *reinterpret_cast<uint4*>(&lsB[m * SA + gq * 8]) = vb;
        }
        __syncthreads();
#pragma unroll
        for (int kk = 0; kk < 2; ++kk) {
            bf16x8 af[4], bfr[4];
            int kg8 = (kk * 4 + lkg) * 8;
#pragma unroll
            for (int mf = 0; mf < 4; ++mf)
                af[mf] = *reinterpret_cast<const bf16x8*>(&lsA[(wm * 64 + mf * 16 + lrow) * SA + kg8]);
#pragma unroll
            for (int nf = 0; nf < 4; ++nf)
                bfr[nf] = *reinterpret_cast<const bf16x8*>(&lsB[(wn * 64 + nf * 16 + lrow) * SA + kg8]);
#pragma unroll
            for (int mf = 0; mf < 4; ++mf)
#pragma unroll
                for (int nf = 0; nf < 4; ++nf)
                    acc[mf][nf] = __builtin_amdgcn_mfma_f32_16x16x32_bf16(af[mf], bfr[nf], acc[mf][nf], 0, 0, 0);
        }
        __syncthreads();
    }

    float mk = 1.f;
    if (MODE == 0) mk = maskp[maskIdx];
#pragma unroll
    for (int mf = 0; mf < 4; ++mf) {
#pragma unroll
        for (int r = 0; r < 4; ++r) {
            int row = rowBase + wm * 64 + mf * 16 + lkg * 4 + r;
            if (row >= M) continue;
            float dv = (MODE == 1) ? dinv[row] : 0.f;
#pragma unroll
            for (int nf = 0; nf < 4; ++nf) {
                int colG = colBase + wn * 64 + nf * 16 + lrow;
                float v = acc[mf][nf][r];
                if (MODE == 0) v = fmaxf(v + bias[colG], 0.f) * mk;
                else           v = v * dv;
                out[((size_t)(colG >> 5) * M + row) * 32 + (colG & 31)] = f2b(v);
            }
        }
    }
}

// ---------------- chunked CSR gather aggregation (XCD-pinned) ----------------
// h chunk-major [8][N][32] bf16; chunk = blockIdx.x & 7 so round-robin block->XCD
// dispatch pins each 3.2MB chunk into one XCD's L2. One wave per node:
// 4 neighbor-slots x 16 lanes (u32 = 2ch each); ILP: 4 gathers in flight.
__global__ __launch_bounds__(256) void agg_chunk(
    const u16* __restrict__ hpC, const int* __restrict__ rp, const u16* __restrict__ colv,
    const float* __restrict__ dinv, const float* __restrict__ bias,
    const float* __restrict__ maskp, int maskIdx, u16* __restrict__ outb, int N) {
    const int c = blockIdx.x & 7;
    const int node = (blockIdx.x >> 3) * 4 + (threadIdx.x >> 6);
    if (node >= N) return;
    const int l = threadIdx.x & 63;
    const int slot = l >> 4, li = l & 15;
    const u32* h32 = reinterpret_cast<const u32*>(hpC) + (size_t)c * N * 16;
    float a0 = 0.f, a1 = 0.f;
    {   // self-loop term (slot 0 only)
        u32 v = h32[(size_t)node * 16 + li];
        if (slot == 0) { a0 += b2f_lo(v); a1 += b2f_hi(v); }
    }
    int beg = rp[node], end = rp[node + 1];
    int j = beg;
    for (; j + 16 <= end; j += 16) {
        int s0 = colv[j + slot];
        int s1 = colv[j + 4 + slot];
        int s2 = colv[j + 8 + slot];
        int s3 = colv[j + 12 + slot];
        u32 v0 = h32[(size_t)s0 * 16 + li];
        u32 v1 = h32[(size_t)s1 * 16 + li];
        u32 v2 = h32[(size_t)s2 * 16 + li];
        u32 v3 = h32[(size_t)s3 * 16 + li];
        a0 += b2f_lo(v0) + b2f_lo(v1) + b2f_lo(v2) + b2f_lo(v3);
        a1 += b2f_hi(v0) + b2f_hi(v1) + b2f_hi(v2) + b2f_hi(v3);
    }
    for (; j + 4 <= end; j += 4) {
        int s = colv[j + slot];
        u32 v = h32[(size_t)s * 16 + li];
        a0 += b2f_lo(v); a1 += b2f_hi(v);
    }
    if (j + slot < end) {
        int s = colv[j + slot];
        u32 v = h32[(size_t)s * 16 + li];
        a0 += b2f_lo(v); a1 += b2f_hi(v);
    }
    a0 += __shfl_xor(a0, 16); a0 += __shfl_xor(a0, 32);
    a1 += __shfl_xor(a1, 16); a1 += __shfl_xor(a1, 32);
    if (slot == 0) {
        float dv = dinv[node];
        float mk = (maskIdx >= 0) ? maskp[maskIdx] : 1.f;
        int ch = c * 32 + li * 2;
        float o0 = fmaxf(fmaf(a0, dv, bias[ch]), 0.f) * mk;
        float o1 = fmaxf(fmaf(a1, dv, bias[ch + 1]), 0.f) * mk;
        reinterpret_cast<u32*>(outb)[((size_t)c * N + node) * 16 + li] =
            (u32)f2b(o0) | ((u32)f2b(o1) << 16);
    }
}

// ---------------- logits ----------------

// out[M][40] (+)= A(chunk-major [8][M][32]) x Wct[48][256]
// FIRST=1: out = acc + bc[col]
template <int FIRST>
__global__ __launch_bounds__(256) void logit_gemm(const u16* __restrict__ A,
                                                  const u16* __restrict__ Wct,
                                                  const float* __restrict__ bc,
                                                  float* __restrict__ out, int M) {
    int l = threadIdx.x & 63;
    int rowBase = blockIdx.x * 64 + (threadIdx.x >> 6) * 16;
    if (rowBase >= M) return;
    int lrow = l & 15, lkg = l >> 4;
    int ar = rowBase + lrow; if (ar >= M) ar = M - 1;
    f32x4 acc[3] = {};
#pragma unroll
    for (int kt = 0; kt < 8; ++kt) {          // kt = chunk
        bf16x8 a = *reinterpret_cast<const bf16x8*>(A + ((size_t)kt * M + ar) * 32 + lkg * 8);
#pragma unroll
        for (int nf = 0; nf < 3; ++nf) {
            bf16x8 b = *reinterpret_cast<const bf16x8*>(Wct + (size_t)(nf * 16 + lrow) * 256 + kt * 32 + lkg * 8);
            acc[nf] = __builtin_amdgcn_mfma_f32_16x16x32_bf16(a, b, acc[nf], 0, 0, 0);
        }
    }
#pragma unroll
    for (int nf = 0; nf < 3; ++nf) {
        int col = nf * 16 + lrow;
        if (col < 40) {
#pragma unroll
            for (int r = 0; r < 4; ++r) {
                int row = rowBase + lkg * 4 + r;
                if (row < M) {
                    if (FIRST) out[(size_t)row * 40 + col] = acc[nf][r] + bc[col];
                    else       out[(size_t)row * 40 + col] += acc[nf][r];
                }
            }
        }
    }
}

__global__ void logsoftmax_k(float* __restrict__ out, int M, int O) {
    int row = blockIdx.x * 4 + (threadIdx.x >> 6);
    if (row >= M) return;
    int l = threadIdx.x & 63;
    float v = (l < O) ? out[(size_t)row * O + l] : -3.4e38f;
    float m = v;
    for (int off = 32; off; off >>= 1) m = fmaxf(m, __shfl_xor(m, off));
    float e = (l < O) ? __expf(v - m) : 0.f;
    float s = e;
    for (int off = 32; off; off >>= 1) s += __shfl_xor(s, off);
    if (l < O) out[(size_t)row * O + l] = v - m - __logf(s);
}

// ---------------- host launch ----------------

extern "C" void kernel_launch(void* const* d_in, const int* in_sizes, int n_in,
                              void* d_out, int out_size, void* d_ws, size_t ws_size,
                              hipStream_t stream) {
    (void)n_in; (void)out_size; (void)ws_size;
    const float* x     = (const float*)d_in[0];
    const int*   ei    = (const int*)d_in[1];
    const int*   nei   = (const int*)d_in[2];
    const float* W_mlp = (const float*)d_in[3];
    const float* b_mlp = (const float*)d_in[4];
    const float* We1   = (const float*)d_in[5];
    const float* be1   = (const float*)d_in[6];
    const float* We2   = (const float*)d_in[7];
    const float* be2   = (const float*)d_in[8];
    const float* Wh    = (const float*)d_in[9];
    const float* bh    = (const float*)d_in[10];
    const float* att   = (const float*)d_in[11];
    const float* Wc    = (const float*)d_in[12];
    const float* bc    = (const float*)d_in[13];
    float* out = (float*)d_out;

    const int N    = in_sizes[0] / 256;     // 50000 (< 65536: u16 cols valid)
    const int E    = in_sizes[1] / 2;       // 1600000
    const int HOPS = in_sizes[10] / 256;    // 3
    const int O    = in_sizes[13];          // 40
    const int SETS = HOPS + 1;              // edge sets: [ei, hop0..2]
    const int NB   = HOPS + 2;              // branches
    const int B    = (N + 255) >> 8;        // buckets (<= 256)

    // workspace carve (256B aligned)
    char* p = (char*)d_ws;
    auto carve = [&](size_t bytes) { char* r = p; p += (bytes + 255) & ~(size_t)255; return r; };
    u16* x16  = (u16*)carve((size_t)N * 256 * 2);
    u16* hA   = (u16*)carve((size_t)N * 256 * 2);   // chunk-major [8][N][32]
    u16* hB   = (u16*)carve((size_t)N * 256 * 2);   // chunk-major
    u16* ebuf = (u16*)carve((size_t)N * 256 * 2);   // chunk-major
    u16* wt   = (u16*)carve((size_t)(3 + HOPS) * 256 * 256 * 2); // [mlp,e1,e2,hop0..]
    u16* wct  = (u16*)carve((size_t)NB * 48 * 256 * 2);
    float* mask = (float*)carve(256);
    float* dinv = (float*)carve((size_t)SETS * N * 4);
    int* rp   = (int*)carve((size_t)SETS * (N + 1) * 4);
    int* bcnt = (int*)carve((size_t)SETS * BMAX * 4);
    int* bbase = (int*)carve((size_t)SETS * BMAX * 4);
    u16* colAll = (u16*)carve((size_t)SETS * E * 2);
    u32* binned = (u32*)hA;   // alias hA+hB (51.2MB >= SETS*BMAX*BCAP*4 = 50.3MB);
                              // binned lifetime ends before any GEMM writes hA/hB

    // packing + mask
    softmax_small<<<1, 64, 0, stream>>>(att, mask, NB);
    {
        long n = (long)N * 256;
        pack_bf16<<<(int)((n / 4 + 255) / 256), 256, 0, stream>>>(x, x16, n);
    }
    {
        dim3 g(256, 3 + HOPS);
        pack_wt_all<<<g, 256, 0, stream>>>(W_mlp, We1, We2, Wh, wt);
    }
    {
        int tot = NB * 48 * 256;
        pack_wct<<<(tot + 255) / 256, 256, 0, stream>>>(Wc, wct, O, NB);
    }

    // bucket-local CSR build
    hipMemsetAsync(bcnt, 0, (size_t)SETS * BMAX * 4, stream);
    {
        dim3 g((E + BINCHUNK - 1) / BINCHUNK, SETS);
        bin_edges<<<g, 256, 0, stream>>>(ei, nei, E, B, bcnt, binned);
    }
    bscan<<<SETS, 256, 0, stream>>>(bcnt, bbase, rp, N, E, B);
    {
        dim3 g(B, SETS);
        bucket_build<<<g, 256, 0, stream>>>(binned, bcnt, bbase, rp, dinv, colAll, E, N);
    }

    dim3 gg((N + 127) / 128, 2);
    const int gl = (N + 63) / 64;
    const int ga = 8 * ((N + 3) / 4);   // chunk = blockIdx.x & 7 (XCD pin)

    // mlp branch -> Wc block NB-1 (FIRST: writes out = acc + bc)
    gemm_k256<0, 0><<<gg, 256, 0, stream>>>(x16, wt, hB, b_mlp, nullptr, mask, 0, N);
    logit_gemm<1><<<gl, 256, 0, stream>>>(hB, wct + (size_t)(NB - 1) * 48 * 256, bc, out, N);

    // hop branches -> Wc blocks 0..HOPS-1, mask[i+1]
    for (int i = 0; i < HOPS; ++i) {
        int s = i + 1;
        gemm_k256<0, 1><<<gg, 256, 0, stream>>>(x16, wt + (size_t)(3 + i) * 65536, hA,
                                                nullptr, dinv + (size_t)s * N, nullptr, 0, N);
        agg_chunk<<<ga, 256, 0, stream>>>(hA, rp + (size_t)s * (N + 1), colAll + (size_t)s * E,
                                          dinv + (size_t)s * N, bh + (size_t)i * 256,
                                          mask, i + 1, hB, N);
        logit_gemm<0><<<gl, 256, 0, stream>>>(hB, wct + (size_t)i * 48 * 256, bc, out, N);
    }

    // e branch: gcn1 (no mask) -> gcn2 (*mask[1]) -> Wc block HOPS
    gemm_k256<0, 1><<<gg, 256, 0, stream>>>(x16, wt + 1 * 65536, hA, nullptr, dinv, nullptr, 0, N);
    agg_chunk<<<ga, 256, 0, stream>>>(hA, rp, colAll, dinv, be1, mask, -1, ebuf, N);
    gemm_k256<1, 1><<<gg, 256, 0, stream>>>(ebuf, wt + 2 * 65536, hA, nullptr, dinv, nullptr, 0, N);
    agg_chunk<<<ga, 256, 0, stream>>>(hA, rp, colAll, dinv, be2, mask, 1, hB, N);
    logit_gemm<0><<<gl, 256, 0, stream>>>(hB, wct + (size_t)HOPS * 48 * 256, bc, out, N);

    // final log-softmax in place on d_out
    logsoftmax_k<<<(N + 3) / 4, 256, 0, stream>>>(out, N, O);
}

// Round 11
// 980.661 us; speedup vs baseline: 1.1881x; 1.1881x over previous
//
#include <hip/hip_runtime.h>
#include <hip/hip_bf16.h>

typedef unsigned short u16;
typedef unsigned int u32;

typedef __bf16 bf16x8 __attribute__((ext_vector_type(8)));
typedef float f32x4 __attribute__((ext_vector_type(4)));

__device__ __forceinline__ float b2f_lo(u32 u) { return __uint_as_float(u << 16); }
__device__ __forceinline__ float b2f_hi(u32 u) { return __uint_as_float(u & 0xffff0000u); }
__device__ __forceinline__ u16 f2b(float f) {
    u32 u = __float_as_uint(f);
    u32 r = u + 0x7fffu + ((u >> 16) & 1u);   // round-to-nearest-even
    return (u16)(r >> 16);
}

#define SA 72                 // LDS row stride in bf16 elems (64 + 8 pad)
#define BSHIFT 8
#define BMAX 256
#define BCAP 12288            // bucket capacity; mean E/B ~8163, +45 sigma
#define BINCHUNK 8192
#define GEMM_SMEM (128 * SA * 2 * 2)            // 36864 B
#define BIN_SMEM  (BINCHUNK * 4 + 5 * BMAX * 4) // 37888 B

// ---------------- job descriptors ----------------
struct GemmJob { const u16* A; const u16* Bt; u16* out; const float* bias;
                 const float* dinv; int maskIdx; int mode; };
struct AggJob  { const u16* hp; const int* rp; const u16* colv; const float* dinv;
                 const float* bias; int maskIdx; u16* outb; };
struct LogitJob{ const u16* A; const u16* Wct; float* out; int first; };

// ---------------- device bodies ----------------

// GEMM [M,256] x [256,256] (Bt transposed), row-major in/out.
// mode 0: relu(acc + bias[col]) * maskp[maskIdx] ; mode 1: acc * dinv[row]
__device__ __forceinline__ void gemm_body(char* smemraw, int bx, int by,
                                          const GemmJob J, const float* maskp, int M) {
    u16* lsA = (u16*)smemraw;
    u16* lsB = (u16*)(smemraw + 128 * SA * 2);
    const int tid = threadIdx.x;
    const int rowBase = bx * 128, colBase = by * 128;
    const int w = tid >> 6, l = tid & 63;
    const int wm = w >> 1, wn = w & 1;
    const int lrow = l & 15, lkg = l >> 4;
    f32x4 acc[4][4] = {};
    for (int kt = 0; kt < 4; ++kt) {
        const int k0 = kt * 64;
#pragma unroll
        for (int q = 0; q < 4; ++q) {
            int g = q * 256 + tid;
            int m = g >> 3, gq = g & 7;
            int grow = rowBase + m;
            int k = k0 + gq * 8;
            uint4 v = make_uint4(0, 0, 0, 0);
            if (grow < M) v = *reinterpret_cast<const uint4*>(J.A + (size_t)grow * 256 + k);
            *reinterpret_cast<uint4*>(&lsA[m * SA + gq * 8]) = v;
            uint4 vb = *reinterpret_cast<const uint4*>(J.Bt + (size_t)(colBase + m) * 256 + k);
            *reinterpret_cast<uint4*>(&lsB[m * SA + gq * 8]) = vb;
        }
        __syncthreads();
#pragma unroll
        for (int kk = 0; kk < 2; ++kk) {
            bf16x8 af[4], bfr[4];
            int kg8 = (kk * 4 + lkg) * 8;
#pragma unroll
            for (int mf = 0; mf < 4; ++mf)
                af[mf] = *reinterpret_cast<const bf16x8*>(&lsA[(wm * 64 + mf * 16 + lrow) * SA + kg8]);
#pragma unroll
            for (int nf = 0; nf < 4; ++nf)
                bfr[nf] = *reinterpret_cast<const bf16x8*>(&lsB[(wn * 64 + nf * 16 + lrow) * SA + kg8]);
#pragma unroll
            for (int mf = 0; mf < 4; ++mf)
#pragma unroll
                for (int nf = 0; nf < 4; ++nf)
                    acc[mf][nf] = __builtin_amdgcn_mfma_f32_16x16x32_bf16(af[mf], bfr[nf], acc[mf][nf], 0, 0, 0);
        }
        __syncthreads();
    }
    float mk = (J.mode == 0) ? maskp[J.maskIdx] : 1.f;
#pragma unroll
    for (int mf = 0; mf < 4; ++mf) {
#pragma unroll
        for (int r = 0; r < 4; ++r) {
            int row = rowBase + wm * 64 + mf * 16 + lkg * 4 + r;
            if (row >= M) continue;
            float dv = (J.mode == 1) ? J.dinv[row] : 0.f;
#pragma unroll
            for (int nf = 0; nf < 4; ++nf) {
                int colG = colBase + wn * 64 + nf * 16 + lrow;
                float v = acc[mf][nf][r];
                if (J.mode == 0) v = fmaxf(v + J.bias[colG], 0.f) * mk;
                else             v = v * dv;
                J.out[(size_t)row * 256 + colG] = f2b(v);
            }
        }
    }
}

// CSR gather aggregation (round-9 form): one wave/node, halves take even/odd
// neighbors, uint4 (16B) per lane -> one instr covers two 512B rows.
__device__ __forceinline__ void agg_body(int blk, const AggJob J, const float* maskp, int N) {
    int node = blk * 4 + (threadIdx.x >> 6);
    if (node >= N) return;
    const int l = threadIdx.x & 63;
    const int h = l >> 5, li = l & 31;
    const uint4* hv = reinterpret_cast<const uint4*>(J.hp);
    float a[8] = {0.f, 0.f, 0.f, 0.f, 0.f, 0.f, 0.f, 0.f};
    {
        uint4 v = hv[(size_t)node * 32 + li];
        if (h == 0) {
            a[0] += b2f_lo(v.x); a[1] += b2f_hi(v.x); a[2] += b2f_lo(v.y); a[3] += b2f_hi(v.y);
            a[4] += b2f_lo(v.z); a[5] += b2f_hi(v.z); a[6] += b2f_lo(v.w); a[7] += b2f_hi(v.w);
        }
    }
    int beg = J.rp[node], end = J.rp[node + 1];
    int j = beg;
    for (; j + 16 <= end; j += 16) {
        int s[8];
#pragma unroll
        for (int q = 0; q < 8; ++q) s[q] = J.colv[j + 2 * q + h];
        uint4 v[8];
#pragma unroll
        for (int q = 0; q < 8; ++q) v[q] = hv[(size_t)s[q] * 32 + li];
#pragma unroll
        for (int q = 0; q < 8; ++q) {
            a[0] += b2f_lo(v[q].x); a[1] += b2f_hi(v[q].x);
            a[2] += b2f_lo(v[q].y); a[3] += b2f_hi(v[q].y);
            a[4] += b2f_lo(v[q].z); a[5] += b2f_hi(v[q].z);
            a[6] += b2f_lo(v[q].w); a[7] += b2f_hi(v[q].w);
        }
    }
    for (; j + 2 <= end; j += 2) {
        int s = J.colv[j + h];
        uint4 v = hv[(size_t)s * 32 + li];
        a[0] += b2f_lo(v.x); a[1] += b2f_hi(v.x); a[2] += b2f_lo(v.y); a[3] += b2f_hi(v.y);
        a[4] += b2f_lo(v.z); a[5] += b2f_hi(v.z); a[6] += b2f_lo(v.w); a[7] += b2f_hi(v.w);
    }
    if (j < end) {
        int s = J.colv[j];
        uint4 v = hv[(size_t)s * 32 + li];
        if (h == 0) {
            a[0] += b2f_lo(v.x); a[1] += b2f_hi(v.x); a[2] += b2f_lo(v.y); a[3] += b2f_hi(v.y);
            a[4] += b2f_lo(v.z); a[5] += b2f_hi(v.z); a[6] += b2f_lo(v.w); a[7] += b2f_hi(v.w);
        }
    }
#pragma unroll
    for (int q = 0; q < 8; ++q) a[q] += __shfl_xor(a[q], 32);
    if (h == 0) {
        float dv = J.dinv[node];
        float mk = (J.maskIdx >= 0) ? maskp[J.maskIdx] : 1.f;
        int ch = li * 8;
        u32 o[4];
#pragma unroll
        for (int q = 0; q < 4; ++q) {
            float e0 = fmaxf(fmaf(a[2 * q + 0], dv, J.bias[ch + 2 * q + 0]), 0.f) * mk;
            float e1 = fmaxf(fmaf(a[2 * q + 1], dv, J.bias[ch + 2 * q + 1]), 0.f) * mk;
            o[q] = (u32)f2b(e0) | ((u32)f2b(e1) << 16);
        }
        reinterpret_cast<uint4*>(J.outb)[(size_t)node * 32 + li] = make_uint4(o[0], o[1], o[2], o[3]);
    }
}

// out[M][40] (+)= A[M][256] x Wct[48][256]; first: out = acc + bc[col]
__device__ __forceinline__ void logit_body(int blk, const LogitJob J, const float* bc, int M) {
    int l = threadIdx.x & 63;
    int rowBase = blk * 64 + (threadIdx.x >> 6) * 16;
    if (rowBase >= M) return;
    int lrow = l & 15, lkg = l >> 4;
    int ar = rowBase + lrow; if (ar >= M) ar = M - 1;
    f32x4 acc[3] = {};
#pragma unroll
    for (int kt = 0; kt < 8; ++kt) {
        bf16x8 a = *reinterpret_cast<const bf16x8*>(J.A + (size_t)ar * 256 + kt * 32 + lkg * 8);
#pragma unroll
        for (int nf = 0; nf < 3; ++nf) {
            bf16x8 b = *reinterpret_cast<const bf16x8*>(J.Wct + (size_t)(nf * 16 + lrow) * 256 + kt * 32 + lkg * 8);
            acc[nf] = __builtin_amdgcn_mfma_f32_16x16x32_bf16(a, b, acc[nf], 0, 0, 0);
        }
    }
#pragma unroll
    for (int nf = 0; nf < 3; ++nf) {
        int col = nf * 16 + lrow;
        if (col < 40) {
#pragma unroll
            for (int r = 0; r < 4; ++r) {
                int row = rowBase + lkg * 4 + r;
                if (row < M) {
                    if (J.first) J.out[(size_t)row * 40 + col] = acc[nf][r] + bc[col];
                    else         J.out[(size_t)row * 40 + col] += acc[nf][r];
                }
            }
        }
    }
}

// bin_edges body: LDS histogram -> per-bucket reservation -> LDS bucket-sort ->
// coalesced bucket-run writes. Entry: src | (d<<16).
__device__ __forceinline__ void bin_body(char* smemraw, int cx, int set,
                                         const int* ei, const int* nei, int E, int B,
                                         int* bcnt, u32* binned) {
    const int* src = (set == 0) ? ei : (nei + (size_t)(set - 1) * 2 * E);
    const int* dst = src + E;
    u32* ebuf = (u32*)smemraw;
    int* hist  = (int*)(smemraw + BINCHUNK * 4);
    int* resv  = hist + BMAX;
    int* lbase = resv + BMAX;
    int* lcur  = lbase + BMAX;
    int* s     = lcur + BMAX;
    int t = threadIdx.x;
    hist[t] = 0; lcur[t] = 0;
    __syncthreads();
    int base = cx * BINCHUNK;
    int lim = min(base + BINCHUNK, E);
    for (int i = base + t; i < lim; i += 256)
        atomicAdd(&hist[dst[i] >> BSHIFT], 1);
    __syncthreads();
    int h = hist[t];
    if (t < B && h > 0) resv[t] = atomicAdd(&bcnt[set * BMAX + t], h);
    s[t] = h;
    __syncthreads();
    for (int off = 1; off < 256; off <<= 1) {
        int x = s[t];
        int add = (t >= off) ? s[t - off] : 0;
        __syncthreads();
        s[t] = x + add;
        __syncthreads();
    }
    lbase[t] = s[t] - h;
    __syncthreads();
    for (int i = base + t; i < lim; i += 256) {
        int d = dst[i];
        int b = d >> BSHIFT;
        int p = atomicAdd(&lcur[b], 1);
        ebuf[lbase[b] + p] = (u32)src[i] | ((u32)d << 16);
    }
    __syncthreads();
    int cnt = lim - base;
    for (int i = t; i < cnt; i += 256) {
        u32 pk = ebuf[i];
        int b = (int)(pk >> (16 + BSHIFT));
        int gpos = resv[b] + (i - lbase[b]);
        if (gpos < BCAP)
            binned[((size_t)set * BMAX + b) * BCAP + gpos] = pk;
    }
}

// bucket_build body: per-(set,bucket) degree histogram -> dinv + rp, then
// scatter u16 colAll with LDS cursors into the bucket's contiguous span.
__device__ __forceinline__ void build_body(char* smemraw, int b, int set,
                                           const u32* binned, const int* bcnt,
                                           const int* bbase, int* rp, float* dinv,
                                           u16* colAll, int E, int N) {
    int t = threadIdx.x;
    int nb = bcnt[set * BMAX + b];
    int base = bbase[set * BMAX + b];
    const u32* bin = binned + ((size_t)set * BMAX + b) * BCAP;
    int* s = (int*)smemraw;
    int* lcur = s + 256;
    s[t] = 0; lcur[t] = 0;
    __syncthreads();
    for (int i = t; i < nb; i += 256)
        atomicAdd(&s[(bin[i] >> 16) & 255], 1);
    __syncthreads();
    int deg = s[t];
    __syncthreads();
    for (int off = 1; off < 256; off <<= 1) {
        int x = s[t];
        int add = (t >= off) ? s[t - off] : 0;
        __syncthreads();
        s[t] = x + add;
        __syncthreads();
    }
    int ex = s[t] - deg;
    __syncthreads();
    s[t] = ex;
    int node = (b << BSHIFT) + t;
    if (node < N) {
        rp[(size_t)set * (N + 1) + node] = base + ex;
        dinv[(size_t)set * N + node] = rsqrtf((float)(deg + 1));
    }
    __syncthreads();
    for (int i = t; i < nb; i += 256) {
        u32 pk = bin[i];
        int dl = (int)((pk >> 16) & 255);
        int pos = base + s[dl] + atomicAdd(&lcur[dl], 1);
        colAll[(size_t)set * E + pos] = (u16)(pk & 0xffffu);
    }
}

// ---------------- mega kernel: co-scheduled jobs, block-range dispatch ----------------
struct MegaArgs {
    int N, E, B, SETS;
    const float* maskp; const float* bc;
    int gemmN, GB; GemmJob g0, g1;
    int binB; const int* ei; const int* nei; int* bcnt; u32* binned;
    int buildB; const int* bbase; int* rp; float* dinv; u16* colAll;
    int LB; LogitJob lj;
    int AB; AggJob aj;
};

__global__ __launch_bounds__(256) void mega(MegaArgs M) {
    extern __shared__ char smem[];
    int b = blockIdx.x;
    int t = M.gemmN * M.GB;
    if (b < t) {
        int j = b / M.GB, lb = b - j * M.GB;
        gemm_body(smem, lb >> 1, lb & 1, j ? M.g1 : M.g0, M.maskp, M.N);
        return;
    }
    b -= t;
    t = M.binB * M.SETS;
    if (b < t) { bin_body(smem, b / M.SETS, b % M.SETS, M.ei, M.nei, M.E, M.B, M.bcnt, M.binned); return; }
    b -= t;
    t = M.buildB * M.SETS;
    if (b < t) { build_body(smem, b / M.SETS, b % M.SETS, M.binned, M.bcnt, M.bbase, M.rp, M.dinv, M.colAll, M.E, M.N); return; }
    b -= t;
    if (b < M.LB) { logit_body(b, M.lj, M.bc, M.N); return; }
    b -= M.LB;
    if (b < M.AB) agg_body(b, M.aj, M.maskp, M.N);
}

// ---------------- standalone wrappers (pure dispatches keep best codegen) ----------------
__global__ __launch_bounds__(256) void gemm_k(GemmJob J, const float* maskp, int M) {
    __shared__ alignas(16) char smem[GEMM_SMEM];
    gemm_body(smem, blockIdx.x, blockIdx.y, J, maskp, M);
}
__global__ __launch_bounds__(256) void agg_k(AggJob J, const float* maskp, int N) {
    agg_body(blockIdx.x, J, maskp, N);
}
__global__ __launch_bounds__(256) void logit_k(LogitJob J, const float* bc, int M) {
    logit_body(blockIdx.x, J, bc, M);
}

// ---------------- small kernels ----------------
__global__ void softmax_small(const float* __restrict__ att, float* __restrict__ mask, int K) {
    if (threadIdx.x == 0) {
        float m = -3.4e38f;
        for (int i = 0; i < K; ++i) m = fmaxf(m, att[i]);
        float s = 0.f;
        for (int i = 0; i < K; ++i) { float e = __expf(att[i] - m); mask[i] = e; s += e; }
        for (int i = 0; i < K; ++i) mask[i] /= s;
    }
}

__global__ void pack_bf16(const float* __restrict__ src, u16* __restrict__ dst, long n) {
    long g = (long)blockIdx.x * 256 + threadIdx.x;
    if (g * 4 >= n) return;
    float4 v = reinterpret_cast<const float4*>(src)[g];
    ushort4 o;
    o.x = f2b(v.x); o.y = f2b(v.y); o.z = f2b(v.z); o.w = f2b(v.w);
    reinterpret_cast<ushort4*>(dst)[g] = o;
}

__global__ void pack_wt_all(const float* __restrict__ W_mlp, const float* __restrict__ We1,
                            const float* __restrict__ We2, const float* __restrict__ Wh,
                            u16* __restrict__ wt) {
    int idx = blockIdx.x * 256 + threadIdx.x;
    int y = blockIdx.y;
    const float* W = (y == 0) ? W_mlp : (y == 1) ? We1 : (y == 2) ? We2
                                      : (Wh + (size_t)(y - 3) * 65536);
    int n = idx >> 8, k = idx & 255;
    wt[(size_t)y * 65536 + idx] = f2b(W[k * 256 + n]);
}

__global__ void pack_wct(const float* __restrict__ Wc, u16* __restrict__ Wct, int O, int NB) {
    int idx = blockIdx.x * 256 + threadIdx.x;
    if (idx >= NB * 48 * 256) return;
    int b = idx / (48 * 256);
    int r = idx - b * 48 * 256;
    int n = r >> 8, k = r & 255;
    float v = (n < O) ? Wc[((size_t)(b * 256 + k)) * O + n] : 0.f;
    Wct[idx] = f2b(v);
}

__global__ void bscan(const int* __restrict__ bcnt, int* __restrict__ bbase,
                      int* __restrict__ rp, int N, int E, int B) {
    int set = blockIdx.x, t = threadIdx.x;
    int v = (t < B) ? bcnt[set * BMAX + t] : 0;
    __shared__ int s[256];
    s[t] = v; __syncthreads();
    for (int off = 1; off < 256; off <<= 1) {
        int x = s[t];
        int add = (t >= off) ? s[t - off] : 0;
        __syncthreads();
        s[t] = x + add;
        __syncthreads();
    }
    bbase[set * BMAX + t] = s[t] - v;
    if (t == 0) rp[(size_t)set * (N + 1) + N] = E;
}

__global__ void logsoftmax_k(float* __restrict__ out, int M, int O) {
    int row = blockIdx.x * 4 + (threadIdx.x >> 6);
    if (row >= M) return;
    int l = threadIdx.x & 63;
    float v = (l < O) ? out[(size_t)row * O + l] : -3.4e38f;
    float m = v;
    for (int off = 32; off; off >>= 1) m = fmaxf(m, __shfl_xor(m, off));
    float e = (l < O) ? __expf(v - m) : 0.f;
    float s = e;
    for (int off = 32; off; off >>= 1) s += __shfl_xor(s, off);
    if (l < O) out[(size_t)row * O + l] = v - m - __logf(s);
}

// ---------------- host launch ----------------

extern "C" void kernel_launch(void* const* d_in, const int* in_sizes, int n_in,
                              void* d_out, int out_size, void* d_ws, size_t ws_size,
                              hipStream_t stream) {
    (void)n_in; (void)out_size; (void)ws_size;
    const float* x     = (const float*)d_in[0];
    const int*   ei    = (const int*)d_in[1];
    const int*   nei   = (const int*)d_in[2];
    const float* W_mlp = (const float*)d_in[3];
    const float* b_mlp = (const float*)d_in[4];
    const float* We1   = (const float*)d_in[5];
    const float* be1   = (const float*)d_in[6];
    const float* We2   = (const float*)d_in[7];
    const float* be2   = (const float*)d_in[8];
    const float* Wh    = (const float*)d_in[9];
    const float* bh    = (const float*)d_in[10];
    const float* att   = (const float*)d_in[11];
    const float* Wc    = (const float*)d_in[12];
    const float* bc    = (const float*)d_in[13];
    float* out = (float*)d_out;

    const int N    = in_sizes[0] / 256;     // 50000 (< 65536)
    const int E    = in_sizes[1] / 2;       // 1600000
    const int HOPS = in_sizes[10] / 256;    // 3
    const int O    = in_sizes[13];          // 40
    const int SETS = HOPS + 1;
    const int NB   = HOPS + 2;
    const int B    = (N + 255) >> 8;

    // workspace carve (256B aligned)
    char* p = (char*)d_ws;
    auto carve = [&](size_t bytes) { char* r = p; p += (bytes + 255) & ~(size_t)255; return r; };
    u16* x16 = (u16*)carve((size_t)N * 256 * 2);
    u16* g0  = (u16*)carve((size_t)N * 256 * 2);
    u16* g1  = (u16*)carve((size_t)N * 256 * 2);
    u16* g2  = (u16*)carve((size_t)N * 256 * 2);
    u16* a0  = (u16*)carve((size_t)N * 256 * 2);
    u16* a1  = (u16*)carve((size_t)N * 256 * 2);
    u16* wt  = (u16*)carve((size_t)(3 + HOPS) * 65536 * 2);
    u16* wct = (u16*)carve((size_t)NB * 48 * 256 * 2);
    float* mask = (float*)carve(256);
    float* dinv = (float*)carve((size_t)SETS * N * 4);
    int* rp    = (int*)carve((size_t)SETS * (N + 1) * 4);
    int* bcnt  = (int*)carve((size_t)SETS * BMAX * 4);
    int* bbase = (int*)carve((size_t)SETS * BMAX * 4);
    u16* colAll = (u16*)carve((size_t)SETS * E * 2);
    u32* binned = (u32*)g2;   // aliases g2+a0 (51.2MB >= SETS*BMAX*BCAP*4 = 50.3MB);
                              // dead after bucket_build, before g2/a0 first written

    const int GB = ((N + 127) / 128) * 2;   // gemm blocks per job
    const int LB = (N + 63) / 64;           // logit blocks
    const int AB = (N + 3) / 4;             // agg blocks
    const int binB = (E + BINCHUNK - 1) / BINCHUNK;

    // weight index helpers
    const u16* wt_mlp = wt + 0 * 65536;
    const u16* wt_e1  = wt + 1 * 65536;
    const u16* wt_e2  = wt + 2 * 65536;
    auto wt_hop = [&](int i) { return wt + (size_t)(3 + i) * 65536; };
    auto wct_b  = [&](int b) { return wct + (size_t)b * 48 * 256; };

    auto mkMega = [&]() { MegaArgs M{}; M.N = N; M.E = E; M.B = B; M.SETS = SETS;
                          M.maskp = mask; M.bc = bc; M.GB = GB; return M; };
    auto launch = [&](MegaArgs& M, int smem) {
        int blocks = M.gemmN * M.GB + M.binB * SETS + M.buildB * SETS + M.LB + M.AB;
        mega<<<blocks, 256, smem, stream>>>(M);
    };

    // --- packing (small) ---
    softmax_small<<<1, 64, 0, stream>>>(att, mask, NB);
    {
        long n = (long)N * 256;
        pack_bf16<<<(int)((n / 4 + 255) / 256), 256, 0, stream>>>(x, x16, n);
    }
    {
        dim3 g(256, 3 + HOPS);
        pack_wt_all<<<g, 256, 0, stream>>>(W_mlp, We1, We2, Wh, wt);
    }
    {
        int tot = NB * 48 * 256;
        pack_wct<<<(tot + 255) / 256, 256, 0, stream>>>(Wc, wct, O, NB);
    }
    hipMemsetAsync(bcnt, 0, (size_t)SETS * BMAX * 4, stream);

    // --- D_b: bin_edges(all sets) || gemm[mlp -> g0, mode0] ---
    {
        MegaArgs M = mkMega();
        M.gemmN = 1;
        M.g0 = GemmJob{x16, wt_mlp, g0, b_mlp, nullptr, 0, 0};
        M.binB = binB; M.ei = ei; M.nei = nei; M.bcnt = bcnt; M.binned = binned;
        launch(M, BIN_SMEM);
    }
    bscan<<<SETS, 256, 0, stream>>>(bcnt, bbase, rp, N, E, B);
    // --- D_d: bucket_build(all sets) || logit[g0, mlp block, FIRST] ---
    {
        MegaArgs M = mkMega();
        M.buildB = B; M.binned = binned; M.bcnt = bcnt; M.bbase = bbase;
        M.rp = rp; M.dinv = dinv; M.colAll = colAll;
        M.LB = LB; M.lj = LogitJob{g0, wct_b(NB - 1), out, 1};
        launch(M, 2048);
    }
    // --- M1: gemm[hop0 -> g1] || gemm[hop1 -> g2] ---
    {
        MegaArgs M = mkMega();
        M.gemmN = 2;
        M.g0 = GemmJob{x16, wt_hop(0), g1, nullptr, dinv + (size_t)1 * N, 0, 1};
        M.g1 = GemmJob{x16, wt_hop(1), g2, nullptr, dinv + (size_t)2 * N, 0, 1};
        launch(M, GEMM_SMEM);
    }
    // --- M2: gemm[hop2 -> g0] || agg[hop0: g1,set1 -> a0] ---
    {
        MegaArgs M = mkMega();
        M.gemmN = 1;
        M.g0 = GemmJob{x16, wt_hop(2), g0, nullptr, dinv + (size_t)3 * N, 0, 1};
        M.AB = AB;
        M.aj = AggJob{g1, rp + (size_t)1 * (N + 1), colAll + (size_t)1 * E,
                      dinv + (size_t)1 * N, bh + 0 * 256, 1, a0};
        launch(M, GEMM_SMEM);
    }
    // --- M3: gemm[e1 -> g1] || logit[a0, block0] || agg[hop1: g2,set2 -> a1] ---
    {
        MegaArgs M = mkMega();
        M.gemmN = 1;
        M.g0 = GemmJob{x16, wt_e1, g1, nullptr, dinv + (size_t)0 * N, 0, 1};
        M.LB = LB; M.lj = LogitJob{a0, wct_b(0), out, 0};
        M.AB = AB;
        M.aj = AggJob{g2, rp + (size_t)2 * (N + 1), colAll + (size_t)2 * E,
                      dinv + (size_t)2 * N, bh + 1 * 256, 2, a1};
        launch(M, GEMM_SMEM);
    }
    // --- M4: logit[a1, block1] || agg[hop2: g0,set3 -> a0] ---
    {
        MegaArgs M = mkMega();
        M.LB = LB; M.lj = LogitJob{a1, wct_b(1), out, 0};
        M.AB = AB;
        M.aj = AggJob{g0, rp + (size_t)3 * (N + 1), colAll + (size_t)3 * E,
                      dinv + (size_t)3 * N, bh + 2 * 256, 3, a0};
        launch(M, 0);
    }
    // --- M5: logit[a0, block2] || agg[e1: g1,set0 -> a1] ---
    {
        MegaArgs M = mkMega();
        M.LB = LB; M.lj = LogitJob{a0, wct_b(2), out, 0};
        M.AB = AB;
        M.aj = AggJob{g1, rp, colAll, dinv, be1, -1, a1};
        launch(M, 0);
    }
    // --- M6: gemm[e2: a1 -> g0] (standalone) ---
    {
        GemmJob J{a1, wt_e2, g0, nullptr, dinv, 0, 1};
        gemm_k<<<dim3(GB / 2, 2), 256, 0, stream>>>(J, mask, N);
    }
    // --- M7: agg[e2: g0,set0 -> a0] (standalone) ---
    {
        AggJob J{g0, rp, colAll, dinv, be2, 1, a0};
        agg_k<<<AB, 256, 0, stream>>>(J, mask, N);
    }
    // --- M8: logit[a0, block3] (standalone) ---
    {
        LogitJob J{a0, wct_b(HOPS), out, 0};
        logit_k<<<LB, 256, 0, stream>>>(J, bc, N);
    }
    // --- final log-softmax ---
    logsoftmax_k<<<(N + 3) / 4, 256, 0, stream>>>(out, N, O);
}

// Round 12
// 899.013 us; speedup vs baseline: 1.2960x; 1.0908x over previous
//
#include <hip/hip_runtime.h>
#include <hip/hip_bf16.h>

typedef unsigned short u16;
typedef unsigned int u32;

typedef __bf16 bf16x8 __attribute__((ext_vector_type(8)));
typedef float f32x4 __attribute__((ext_vector_type(4)));

__device__ __forceinline__ float b2f_lo(u32 u) { return __uint_as_float(u << 16); }
__device__ __forceinline__ float b2f_hi(u32 u) { return __uint_as_float(u & 0xffff0000u); }
__device__ __forceinline__ u16 f2b(float f) {
    u32 u = __float_as_uint(f);
    u32 r = u + 0x7fffu + ((u >> 16) & 1u);   // round-to-nearest-even
    return (u16)(r >> 16);
}

#define SA 72                 // LDS row stride in bf16 elems (64 + 8 pad)
#define BSHIFT 8
#define BMAX 256
#define BCAP 12288            // bucket capacity; mean E/B ~8163
#define BINCHUNK 4096         // 21.5KB LDS -> ~7 blocks/CU, 1564 blocks
#define GEMM_SMEM (128 * SA * 2 * 2)

// ---------------- fused packing: x->bf16, weights, Wc, bcnt zero, att softmax ----------------
__global__ void pack_all(const float* __restrict__ x, u16* __restrict__ x16, int PB, int N,
                         const float* __restrict__ W_mlp, const float* __restrict__ We1,
                         const float* __restrict__ We2, const float* __restrict__ Wh,
                         u16* __restrict__ wt, int HOPS,
                         const float* __restrict__ Wc, u16* __restrict__ wct, int O, int NB, int WCB,
                         const float* __restrict__ att, float* __restrict__ mask,
                         int* __restrict__ bcnt, int SETS) {
    int b = blockIdx.x, t = threadIdx.x;
    if (b < PB) {                                   // x f32 -> bf16 (float4/thread)
        long g = (long)b * 256 + t;
        if (g * 4 < (long)N * 256) {
            float4 v = reinterpret_cast<const float4*>(x)[g];
            ushort4 o; o.x = f2b(v.x); o.y = f2b(v.y); o.z = f2b(v.z); o.w = f2b(v.w);
            reinterpret_cast<ushort4*>(x16)[g] = o;
        }
        return;
    }
    b -= PB;
    int WB = (3 + HOPS) * 256;
    if (b < WB) {                                   // transpose-pack 6 weight mats
        int y = b >> 8, ib = b & 255;
        const float* W = (y == 0) ? W_mlp : (y == 1) ? We1 : (y == 2) ? We2
                                          : (Wh + (size_t)(y - 3) * 65536);
        int idx = ib * 256 + t;
        int n = idx >> 8, k = idx & 255;
        wt[(size_t)y * 65536 + idx] = f2b(W[k * 256 + n]);
        return;
    }
    b -= WB;
    if (b < WCB) {                                  // Wc -> per-branch transposed, padded
        int idx = b * 256 + t;
        if (idx < NB * 48 * 256) {
            int bb = idx / (48 * 256), r = idx - bb * 48 * 256;
            int n = r >> 8, k = r & 255;
            float v = (n < O) ? Wc[((size_t)(bb * 256 + k)) * O + n] : 0.f;
            wct[idx] = f2b(v);
        }
        return;
    }
    // final block: zero bcnt + branch-attention softmax
    for (int i = t; i < SETS * BMAX; i += 256) bcnt[i] = 0;
    if (t == 0) {
        float m = -3.4e38f;
        for (int i = 0; i < NB; ++i) m = fmaxf(m, att[i]);
        float s = 0.f;
        for (int i = 0; i < NB; ++i) { float e = __expf(att[i] - m); mask[i] = e; s += e; }
        for (int i = 0; i < NB; ++i) mask[i] /= s;
    }
}

// ---------------- bucket-local CSR build ----------------

// LDS histogram -> per-bucket reservation -> LDS bucket-sort -> coalesced runs.
__global__ __launch_bounds__(256) void bin_edges(
    const int* __restrict__ ei, const int* __restrict__ nei, int E, int B,
    int* __restrict__ bcnt, u32* __restrict__ binned) {
    int set = blockIdx.y;
    const int* src = (set == 0) ? ei : (nei + (size_t)(set - 1) * 2 * E);
    const int* dst = src + E;
    __shared__ u32 ebuf[BINCHUNK];
    __shared__ int hist[BMAX], resv[BMAX], lbase[BMAX], lcur[BMAX], s[BMAX];
    int t = threadIdx.x;
    hist[t] = 0; lcur[t] = 0;
    __syncthreads();
    int base = blockIdx.x * BINCHUNK;
    int lim = min(base + BINCHUNK, E);
    for (int i = base + t; i < lim; i += 256)
        atomicAdd(&hist[dst[i] >> BSHIFT], 1);
    __syncthreads();
    int h = hist[t];
    if (t < B && h > 0) resv[t] = atomicAdd(&bcnt[set * BMAX + t], h);
    s[t] = h;
    __syncthreads();
    for (int off = 1; off < 256; off <<= 1) {
        int x = s[t];
        int add = (t >= off) ? s[t - off] : 0;
        __syncthreads();
        s[t] = x + add;
        __syncthreads();
    }
    lbase[t] = s[t] - h;
    __syncthreads();
    for (int i = base + t; i < lim; i += 256) {
        int d = dst[i];
        int b = d >> BSHIFT;
        int p = atomicAdd(&lcur[b], 1);
        ebuf[lbase[b] + p] = (u32)src[i] | ((u32)d << 16);
    }
    __syncthreads();
    int cnt = lim - base;
    for (int i = t; i < cnt; i += 256) {
        u32 pk = ebuf[i];
        int b = (int)(pk >> (16 + BSHIFT));
        int gpos = resv[b] + (i - lbase[b]);
        if (gpos < BCAP)
            binned[((size_t)set * BMAX + b) * BCAP + gpos] = pk;
    }
}

__global__ void bscan(const int* __restrict__ bcnt, int* __restrict__ bbase,
                      int* __restrict__ rp, int N, int E, int B) {
    int set = blockIdx.x, t = threadIdx.x;
    int v = (t < B) ? bcnt[set * BMAX + t] : 0;
    __shared__ int s[256];
    s[t] = v; __syncthreads();
    for (int off = 1; off < 256; off <<= 1) {
        int x = s[t];
        int add = (t >= off) ? s[t - off] : 0;
        __syncthreads();
        s[t] = x + add;
        __syncthreads();
    }
    bbase[set * BMAX + t] = s[t] - v;
    if (t == 0) rp[(size_t)set * (N + 1) + N] = E;
}

__global__ __launch_bounds__(256) void bucket_build(
    const u32* __restrict__ binned, const int* __restrict__ bcnt,
    const int* __restrict__ bbase, int* __restrict__ rp, float* __restrict__ dinv,
    u16* __restrict__ colAll, int E, int N) {
    int set = blockIdx.y;
    int b = blockIdx.x;
    int t = threadIdx.x;
    int nb = bcnt[set * BMAX + b];
    int base = bbase[set * BMAX + b];
    const u32* bin = binned + ((size_t)set * BMAX + b) * BCAP;
    __shared__ int s[256], lcur[256];
    s[t] = 0; lcur[t] = 0;
    __syncthreads();
    for (int i = t; i < nb; i += 256)
        atomicAdd(&s[(bin[i] >> 16) & 255], 1);
    __syncthreads();
    int deg = s[t];
    __syncthreads();
    for (int off = 1; off < 256; off <<= 1) {
        int x = s[t];
        int add = (t >= off) ? s[t - off] : 0;
        __syncthreads();
        s[t] = x + add;
        __syncthreads();
    }
    int ex = s[t] - deg;
    __syncthreads();
    s[t] = ex;
    int node = (b << BSHIFT) + t;
    if (node < N) {
        rp[(size_t)set * (N + 1) + node] = base + ex;
        dinv[(size_t)set * N + node] = rsqrtf((float)(deg + 1));
    }
    __syncthreads();
    for (int i = t; i < nb; i += 256) {
        u32 pk = bin[i];
        int dl = (int)((pk >> 16) & 255);
        int pos = base + s[dl] + atomicAdd(&lcur[dl], 1);
        colAll[(size_t)set * E + pos] = (u16)(pk & 0xffffu);
    }
}

// ---------------- GEMM body: [M,256] x [256,256] (Bt transposed), row-major ----------------
// mode 0: relu(acc + bias[col]) * maskp[0] ; mode 1: acc * dinv[row]
__device__ __forceinline__ void gemm_body(char* smemraw, int bx, int by,
                                          const u16* __restrict__ A, const u16* __restrict__ Bt,
                                          u16* __restrict__ out, const float* bias,
                                          const float* dinv, int mode,
                                          const float* maskp, int M) {
    u16* lsA = (u16*)smemraw;
    u16* lsB = (u16*)(smemraw + 128 * SA * 2);
    const int tid = threadIdx.x;
    const int rowBase = bx * 128, colBase = by * 128;
    const int w = tid >> 6, l = tid & 63;
    const int wm = w >> 1, wn = w & 1;
    const int lrow = l & 15, lkg = l >> 4;
    f32x4 acc[4][4] = {};
    for (int kt = 0; kt < 4; ++kt) {
        const int k0 = kt * 64;
#pragma unroll
        for (int q = 0; q < 4; ++q) {
            int g = q * 256 + tid;
            int m = g >> 3, gq = g & 7;
            int grow = rowBase + m;
            int k = k0 + gq * 8;
            uint4 v = make_uint4(0, 0, 0, 0);
            if (grow < M) v = *reinterpret_cast<const uint4*>(A + (size_t)grow * 256 + k);
            *reinterpret_cast<uint4*>(&lsA[m * SA + gq * 8]) = v;
            uint4 vb = *reinterpret_cast<const uint4*>(Bt + (size_t)(colBase + m) * 256 + k);
            *reinterpret_cast<uint4*>(&lsB[m * SA + gq * 8]) = vb;
        }
        __syncthreads();
#pragma unroll
        for (int kk = 0; kk < 2; ++kk) {
            bf16x8 af[4], bfr[4];
            int kg8 = (kk * 4 + lkg) * 8;
#pragma unroll
            for (int mf = 0; mf < 4; ++mf)
                af[mf] = *reinterpret_cast<const bf16x8*>(&lsA[(wm * 64 + mf * 16 + lrow) * SA + kg8]);
#pragma unroll
            for (int nf = 0; nf < 4; ++nf)
                bfr[nf] = *reinterpret_cast<const bf16x8*>(&lsB[(wn * 64 + nf * 16 + lrow) * SA + kg8]);
#pragma unroll
            for (int mf = 0; mf < 4; ++mf)
#pragma unroll
                for (int nf = 0; nf < 4; ++nf)
                    acc[mf][nf] = __builtin_amdgcn_mfma_f32_16x16x32_bf16(af[mf], bfr[nf], acc[mf][nf], 0, 0, 0);
        }
        __syncthreads();
    }
    float mk = (mode == 0) ? maskp[0] : 1.f;
#pragma unroll
    for (int mf = 0; mf < 4; ++mf) {
#pragma unroll
        for (int r = 0; r < 4; ++r) {
            int row = rowBase + wm * 64 + mf * 16 + lkg * 4 + r;
            if (row >= M) continue;
            float dv = (mode == 1) ? dinv[row] : 0.f;
#pragma unroll
            for (int nf = 0; nf < 4; ++nf) {
                int colG = colBase + wn * 64 + nf * 16 + lrow;
                float v = acc[mf][nf][r];
                if (mode == 0) v = fmaxf(v + bias[colG], 0.f) * mk;
                else           v = v * dv;
                out[(size_t)row * 256 + colG] = f2b(v);
            }
        }
    }
}

// fused 5-branch shared-A GEMM: blockIdx.y = branch*2 + colHalf
__global__ __launch_bounds__(256) void gemm5(
    const u16* __restrict__ A, const u16* __restrict__ wt,
    u16* o_mlp, u16* o_h0, u16* o_h1, u16* o_h2, u16* o_e1,
    const float* __restrict__ b_mlp, const float* __restrict__ dinv,
    const float* __restrict__ maskp, int N) {
    __shared__ alignas(16) char smem[GEMM_SMEM];
    int br = blockIdx.y >> 1, half = blockIdx.y & 1;
    const u16* Bt; u16* out; const float* dv = nullptr; int mode;
    if (br == 0)      { Bt = wt;              out = o_mlp; mode = 0; }
    else if (br == 1) { Bt = wt + 3 * 65536;  out = o_h0;  mode = 1; dv = dinv + (size_t)1 * N; }
    else if (br == 2) { Bt = wt + 4 * 65536;  out = o_h1;  mode = 1; dv = dinv + (size_t)2 * N; }
    else if (br == 3) { Bt = wt + 5 * 65536;  out = o_h2;  mode = 1; dv = dinv + (size_t)3 * N; }
    else              { Bt = wt + 1 * 65536;  out = o_e1;  mode = 1; dv = dinv; }
    gemm_body(smem, blockIdx.x, half, A, Bt, out, b_mlp, dv, mode, maskp, N);
}

// standalone GEMM (e2 branch, mode 1)
__global__ __launch_bounds__(256) void gemm_k(const u16* __restrict__ A, const u16* __restrict__ Bt,
                                              u16* __restrict__ out, const float* __restrict__ dinv,
                                              int M) {
    __shared__ alignas(16) char smem[GEMM_SMEM];
    gemm_body(smem, blockIdx.x, blockIdx.y, A, Bt, out, nullptr, dinv, 1, nullptr, M);
}

// ---------------- CSR gather aggregation (round-9 form, u16 cols) ----------------
// One wave/node; halves take even/odd neighbors; uint4/lane = one instr per two rows.
__global__ __launch_bounds__(256) void agg_gcn(
    const u16* __restrict__ hp, const int* __restrict__ rp, const u16* __restrict__ colv,
    const float* __restrict__ dinv, const float* __restrict__ bias,
    const float* __restrict__ maskp, int maskIdx, u16* __restrict__ outb, int N) {
    int node = blockIdx.x * 4 + (threadIdx.x >> 6);
    if (node >= N) return;
    const int l = threadIdx.x & 63;
    const int h = l >> 5, li = l & 31;
    const uint4* hv = reinterpret_cast<const uint4*>(hp);
    float a[8] = {0.f, 0.f, 0.f, 0.f, 0.f, 0.f, 0.f, 0.f};
    {
        uint4 v = hv[(size_t)node * 32 + li];
        if (h == 0) {
            a[0] += b2f_lo(v.x); a[1] += b2f_hi(v.x); a[2] += b2f_lo(v.y); a[3] += b2f_hi(v.y);
            a[4] += b2f_lo(v.z); a[5] += b2f_hi(v.z); a[6] += b2f_lo(v.w); a[7] += b2f_hi(v.w);
        }
    }
    int beg = rp[node], end = rp[node + 1];
    int j = beg;
    for (; j + 16 <= end; j += 16) {
        int s[8];
#pragma unroll
        for (int q = 0; q < 8; ++q) s[q] = colv[j + 2 * q + h];
        uint4 v[8];
#pragma unroll
        for (int q = 0; q < 8; ++q) v[q] = hv[(size_t)s[q] * 32 + li];
#pragma unroll
        for (int q = 0; q < 8; ++q) {
            a[0] += b2f_lo(v[q].x); a[1] += b2f_hi(v[q].x);
            a[2] += b2f_lo(v[q].y); a[3] += b2f_hi(v[q].y);
            a[4] += b2f_lo(v[q].z); a[5] += b2f_hi(v[q].z);
            a[6] += b2f_lo(v[q].w); a[7] += b2f_hi(v[q].w);
        }
    }
    for (; j + 2 <= end; j += 2) {
        int s = colv[j + h];
        uint4 v = hv[(size_t)s * 32 + li];
        a[0] += b2f_lo(v.x); a[1] += b2f_hi(v.x); a[2] += b2f_lo(v.y); a[3] += b2f_hi(v.y);
        a[4] += b2f_lo(v.z); a[5] += b2f_hi(v.z); a[6] += b2f_lo(v.w); a[7] += b2f_hi(v.w);
    }
    if (j < end) {
        int s = colv[j];
        uint4 v = hv[(size_t)s * 32 + li];
        if (h == 0) {
            a[0] += b2f_lo(v.x); a[1] += b2f_hi(v.x); a[2] += b2f_lo(v.y); a[3] += b2f_hi(v.y);
            a[4] += b2f_lo(v.z); a[5] += b2f_hi(v.z); a[6] += b2f_lo(v.w); a[7] += b2f_hi(v.w);
        }
    }
#pragma unroll
    for (int q = 0; q < 8; ++q) a[q] += __shfl_xor(a[q], 32);
    if (h == 0) {
        float dv = dinv[node];
        float mk = (maskIdx >= 0) ? maskp[maskIdx] : 1.f;
        int ch = li * 8;
        u32 o[4];
#pragma unroll
        for (int q = 0; q < 4; ++q) {
            float e0 = fmaxf(fmaf(a[2 * q + 0], dv, bias[ch + 2 * q + 0]), 0.f) * mk;
            float e1 = fmaxf(fmaf(a[2 * q + 1], dv, bias[ch + 2 * q + 1]), 0.f) * mk;
            o[q] = (u32)f2b(e0) | ((u32)f2b(e1) << 16);
        }
        reinterpret_cast<uint4*>(outb)[(size_t)node * 32 + li] = make_uint4(o[0], o[1], o[2], o[3]);
    }
}

// ---------------- logits ----------------
template <int FIRST>
__global__ __launch_bounds__(256) void logit_gemm(const u16* __restrict__ A,
                                                  const u16* __restrict__ Wct,
                                                  const float* __restrict__ bc,
                                                  float* __restrict__ out, int M) {
    int l = threadIdx.x & 63;
    int rowBase = blockIdx.x * 64 + (threadIdx.x >> 6) * 16;
    if (rowBase >= M) return;
    int lrow = l & 15, lkg = l >> 4;
    int ar = rowBase + lrow; if (ar >= M) ar = M - 1;
    f32x4 acc[3] = {};
#pragma unroll
    for (int kt = 0; kt < 8; ++kt) {
        bf16x8 a = *reinterpret_cast<const bf16x8*>(A + (size_t)ar * 256 + kt * 32 + lkg * 8);
#pragma unroll
        for (int nf = 0; nf < 3; ++nf) {
            bf16x8 b = *reinterpret_cast<const bf16x8*>(Wct + (size_t)(nf * 16 + lrow) * 256 + kt * 32 + lkg * 8);
            acc[nf] = __builtin_amdgcn_mfma_f32_16x16x32_bf16(a, b, acc[nf], 0, 0, 0);
        }
    }
#pragma unroll
    for (int nf = 0; nf < 3; ++nf) {
        int col = nf * 16 + lrow;
        if (col < 40) {
#pragma unroll
            for (int r = 0; r < 4; ++r) {
                int row = rowBase + lkg * 4 + r;
                if (row < M) {
                    if (FIRST) out[(size_t)row * 40 + col] = acc[nf][r] + bc[col];
                    else       out[(size_t)row * 40 + col] += acc[nf][r];
                }
            }
        }
    }
}

__global__ void logsoftmax_k(float* __restrict__ out, int M, int O) {
    int row = blockIdx.x * 4 + (threadIdx.x >> 6);
    if (row >= M) return;
    int l = threadIdx.x & 63;
    float v = (l < O) ? out[(size_t)row * O + l] : -3.4e38f;
    float m = v;
    for (int off = 32; off; off >>= 1) m = fmaxf(m, __shfl_xor(m, off));
    float e = (l < O) ? __expf(v - m) : 0.f;
    float s = e;
    for (int off = 32; off; off >>= 1) s += __shfl_xor(s, off);
    if (l < O) out[(size_t)row * O + l] = v - m - __logf(s);
}

// ---------------- host launch ----------------

extern "C" void kernel_launch(void* const* d_in, const int* in_sizes, int n_in,
                              void* d_out, int out_size, void* d_ws, size_t ws_size,
                              hipStream_t stream) {
    (void)n_in; (void)out_size; (void)ws_size;
    const float* x     = (const float*)d_in[0];
    const int*   ei    = (const int*)d_in[1];
    const int*   nei   = (const int*)d_in[2];
    const float* W_mlp = (const float*)d_in[3];
    const float* b_mlp = (const float*)d_in[4];
    const float* We1   = (const float*)d_in[5];
    const float* be1   = (const float*)d_in[6];
    const float* We2   = (const float*)d_in[7];
    const float* be2   = (const float*)d_in[8];
    const float* Wh    = (const float*)d_in[9];
    const float* bh    = (const float*)d_in[10];
    const float* att   = (const float*)d_in[11];
    const float* Wc    = (const float*)d_in[12];
    const float* bc    = (const float*)d_in[13];
    float* out = (float*)d_out;

    const int N    = in_sizes[0] / 256;     // 50000 (< 65536)
    const int E    = in_sizes[1] / 2;       // 1600000
    const int HOPS = in_sizes[10] / 256;    // 3
    const int O    = in_sizes[13];          // 40
    const int SETS = HOPS + 1;
    const int NB   = HOPS + 2;
    const int B    = (N + 255) >> 8;

    // workspace carve (256B aligned; all big buffers are exact multiples of 256B)
    char* p = (char*)d_ws;
    auto carve = [&](size_t bytes) { char* r = p; p += (bytes + 255) & ~(size_t)255; return r; };
    u16* x16   = (u16*)carve((size_t)N * 256 * 2);
    u16* o_mlp = (u16*)carve((size_t)N * 256 * 2);
    u16* o_h0  = (u16*)carve((size_t)N * 256 * 2);
    u16* o_h1  = (u16*)carve((size_t)N * 256 * 2);
    u16* o_h2  = (u16*)carve((size_t)N * 256 * 2);
    u16* o_e1  = (u16*)carve((size_t)N * 256 * 2);
    u16* wt    = (u16*)carve((size_t)(3 + HOPS) * 65536 * 2);
    u16* wct   = (u16*)carve((size_t)NB * 48 * 256 * 2);
    float* mask = (float*)carve(256);
    float* dinv = (float*)carve((size_t)SETS * N * 4);
    int* rp    = (int*)carve((size_t)SETS * (N + 1) * 4);
    int* bcnt  = (int*)carve((size_t)SETS * BMAX * 4);
    int* bbase = (int*)carve((size_t)SETS * BMAX * 4);
    u16* colAll = (u16*)carve((size_t)SETS * E * 2);
    u32* binned = (u32*)o_h0;   // aliases o_h0+o_h1 (51.2MB >= SETS*BMAX*BCAP*4 = 50.3MB);
                                // dead after bucket_build; o_h0/o_h1 first written by gemm5

    const int PB  = (N * 64 + 255) / 256;            // x-pack blocks (float4/thread)
    const int WCB = (NB * 48 * 256 + 255) / 256;     // Wc-pack blocks
    const int GB  = (N + 127) / 128;
    const int LB  = (N + 63) / 64;
    const int AB  = (N + 3) / 4;
    auto wct_b = [&](int b) { return wct + (size_t)b * 48 * 256; };

    // 1. fused packing (+ bcnt zero + att softmax)
    {
        int grid = PB + (3 + HOPS) * 256 + WCB + 1;
        pack_all<<<grid, 256, 0, stream>>>(x, x16, PB, N, W_mlp, We1, We2, Wh, wt, HOPS,
                                           Wc, wct, O, NB, WCB, att, mask, bcnt, SETS);
    }
    // 2. CSR build
    {
        dim3 g((E + BINCHUNK - 1) / BINCHUNK, SETS);
        bin_edges<<<g, 256, 0, stream>>>(ei, nei, E, B, bcnt, binned);
    }
    bscan<<<SETS, 256, 0, stream>>>(bcnt, bbase, rp, N, E, B);
    {
        dim3 g(B, SETS);
        bucket_build<<<g, 256, 0, stream>>>(binned, bcnt, bbase, rp, dinv, colAll, E, N);
    }
    // 3. fused 5-branch GEMM (mlp, hop0-2, e1; all read x16)
    gemm5<<<dim3(GB, 10), 256, 0, stream>>>(x16, wt, o_mlp, o_h0, o_h1, o_h2, o_e1,
                                            b_mlp, dinv, mask, N);
    // 4. mlp logit (FIRST: out = acc + bc)
    logit_gemm<1><<<LB, 256, 0, stream>>>(o_mlp, wct_b(NB - 1), bc, out, N);
    // 5. hop branches (buffer rotation: freed buffers host agg outputs)
    agg_gcn<<<AB, 256, 0, stream>>>(o_h0, rp + (size_t)1 * (N + 1), colAll + (size_t)1 * E,
                                    dinv + (size_t)1 * N, bh + 0 * 256, mask, 1, o_mlp, N);
    logit_gemm<0><<<LB, 256, 0, stream>>>(o_mlp, wct_b(0), bc, out, N);
    agg_gcn<<<AB, 256, 0, stream>>>(o_h1, rp + (size_t)2 * (N + 1), colAll + (size_t)2 * E,
                                    dinv + (size_t)2 * N, bh + 1 * 256, mask, 2, o_h0, N);
    logit_gemm<0><<<LB, 256, 0, stream>>>(o_h0, wct_b(1), bc, out, N);
    agg_gcn<<<AB, 256, 0, stream>>>(o_h2, rp + (size_t)3 * (N + 1), colAll + (size_t)3 * E,
                                    dinv + (size_t)3 * N, bh + 2 * 256, mask, 3, o_h1, N);
    logit_gemm<0><<<LB, 256, 0, stream>>>(o_h1, wct_b(2), bc, out, N);
    // 6. e branch: agg(e1) -> gemm(We2) -> agg(e2, *mask[1]) -> logit
    agg_gcn<<<AB, 256, 0, stream>>>(o_e1, rp, colAll, dinv, be1, mask, -1, o_h2, N);
    gemm_k<<<dim3(GB, 2), 256, 0, stream>>>(o_h2, wt + 2 * 65536, o_e1, dinv, N);
    agg_gcn<<<AB, 256, 0, stream>>>(o_e1, rp, colAll, dinv, be2, mask, 1, o_h2, N);
    logit_gemm<0><<<LB, 256, 0, stream>>>(o_h2, wct_b(HOPS), bc, out, N);
    // 7. final log-softmax
    logsoftmax_k<<<(N + 3) / 4, 256, 0, stream>>>(out, N, O);
}